// Round 10
// baseline (4380.148 us; speedup 1.0000x reference)
//
#include <hip/hip_runtime.h>
#include <cstdint>
#include <cstddef>

#define HID 3000
#define HP  3072          // padded hidden (2^10 * 3)
#define NB  1024          // batch
#define BM  128           // mlp3 tile
#define BN  64            // mlp3 per-tile N
#define NSLAB 96          // HP/32 K-slabs for gru
#define SLAB 17408        // slab: A 128x32 f16 (8KB) + B 144x32 f16 (9216B)

typedef _Float16 f16;
typedef _Float16 f16x8 __attribute__((ext_vector_type(8)));
typedef float    f32x4 __attribute__((ext_vector_type(4)));

__device__ __forceinline__ float sigf(float v)  { return 1.0f / (1.0f + __expf(-v)); }
__device__ __forceinline__ float tanhf_(float v){ return 2.0f / (1.0f + __expf(-2.0f * v)) - 1.0f; }

// async global->LDS, 16B per lane. LDS dest = wave-uniform base + lane*16 (linear).
__device__ __forceinline__ void gload16(const void* g, void* l) {
    __builtin_amdgcn_global_load_lds((const __attribute__((address_space(1))) void*)g,
                                     (__attribute__((address_space(3))) void*)l, 16, 0, 0);
}

// ---------------- Whh fp32 -> fp16, padded [3][HP][HP]; 128B-in/64B-out per thread
__global__ __launch_bounds__(256) void convert_whh(const float* __restrict__ whh,
                                                   f16* __restrict__ whh16)
{
    const int S32 = 3 * HP * (HP / 32);
    int t = blockIdx.x * 256 + threadIdx.x;
    if (t >= S32) return;
    const int c32 = (t % (HP / 32)) * 32;
    const int rr  = (t / (HP / 32)) % HP;
    const int g   = t / ((HP / 32) * HP);
    f16* dst = whh16 + ((size_t)g * HP + rr) * HP + c32;
    if (rr < HID && c32 + 32 <= HID) {
        const float* src = whh + (size_t)(g * HID + rr) * HID + c32;
#pragma unroll
        for (int u = 0; u < 4; ++u) {
            float4 lo = *reinterpret_cast<const float4*>(src + u * 8);
            float4 hi = *reinterpret_cast<const float4*>(src + u * 8 + 4);
            f16x8 v;
            v[0] = (f16)lo.x; v[1] = (f16)lo.y; v[2] = (f16)lo.z; v[3] = (f16)lo.w;
            v[4] = (f16)hi.x; v[5] = (f16)hi.y; v[6] = (f16)hi.z; v[7] = (f16)hi.w;
            *reinterpret_cast<f16x8*>(dst + u * 8) = v;
        }
    } else {
#pragma unroll
        for (int u = 0; u < 4; ++u) {
            f16x8 v;
#pragma unroll
            for (int k = 0; k < 8; ++k) {
                const int cc = c32 + u * 8 + k;
                v[k] = (rr < HID && cc < HID) ? (f16)whh[(size_t)(g * HID + rr) * HID + cc]
                                              : (f16)0.0f;
            }
            *reinterpret_cast<f16x8*>(dst + u * 8) = v;
        }
    }
}

// ---------------- W3 fp32 [3000][256] -> f16 [HP][256], zero-padded rows
__global__ __launch_bounds__(256) void convert_w3(const float* __restrict__ w,
                                                  f16* __restrict__ w16)
{
    int t = blockIdx.x * 256 + threadIdx.x;      // HP * 32 slots of 8
    if (t >= HP * 32) return;
    int rr = t >> 5, c8 = (t & 31) * 8;
    f16x8 v;
    if (rr < HID) {
        const float* src = w + (size_t)rr * 256 + c8;
        float4 lo = *reinterpret_cast<const float4*>(src);
        float4 hi = *reinterpret_cast<const float4*>(src + 4);
        v[0] = (f16)lo.x; v[1] = (f16)lo.y; v[2] = (f16)lo.z; v[3] = (f16)lo.w;
        v[4] = (f16)hi.x; v[5] = (f16)hi.y; v[6] = (f16)hi.z; v[7] = (f16)hi.w;
    } else {
#pragma unroll
        for (int i = 0; i < 8; ++i) v[i] = (f16)0.0f;
    }
    *reinterpret_cast<f16x8*>(w16 + (size_t)rr * 256 + c8) = v;
}

// ---------------- small fp32 MLP layer: out = relu(A @ W^T + b), optional f16 copy
__global__ __launch_bounds__(256) void mlp_layer(const float* __restrict__ A, int K, int N, int ldo,
                                                 const float* __restrict__ W,
                                                 const float* __restrict__ bias,
                                                 float* __restrict__ outf, f16* __restrict__ outh)
{
    __shared__ float sA[4 * 512];
    const int b0 = blockIdx.x * 4;
    for (int idx = threadIdx.x; idx < 4 * K; idx += 256)
        sA[idx] = A[(size_t)b0 * K + idx];
    __syncthreads();
    for (int n = threadIdx.x; n < ldo; n += 256) {
        float acc[4] = {0.f, 0.f, 0.f, 0.f};
        if (n < N) {
            const float4* wr = reinterpret_cast<const float4*>(W + (size_t)n * K);
            for (int kk = 0; kk < (K >> 2); ++kk) {
                float4 w = wr[kk];
#pragma unroll
                for (int r = 0; r < 4; ++r) {
                    const float* ar = sA + r * K + kk * 4;
                    acc[r] += ar[0] * w.x + ar[1] * w.y + ar[2] * w.z + ar[3] * w.w;
                }
            }
            float bv = bias[n];
#pragma unroll
            for (int r = 0; r < 4; ++r) acc[r] = fmaxf(acc[r] + bv, 0.f);
        }
#pragma unroll
        for (int r = 0; r < 4; ++r) {
            outf[(size_t)(b0 + r) * ldo + n] = acc[r];
            if (outh) outh[(size_t)(b0 + r) * ldo + n] = (f16)acc[r];
        }
    }
}

// ---------------- W3 layer via MFMA: out = relu(A @ B^T + b3); A [NB][256] f16, B [HP][256] f16
__global__ __launch_bounds__(256, 2)
void mlp3_mfma(const f16* __restrict__ A, const f16* __restrict__ B,
               const float* __restrict__ bias,
               float* __restrict__ outf, f16* __restrict__ outh)
{
    __shared__ __align__(16) char smem[24576];   // sA 16KB | sB 8KB
    char* sBm = smem + 16384;

    const int tid  = threadIdx.x;
    const int lane = tid & 63;
    const int wid  = tid >> 6;
    const int wm = wid >> 1, wn = wid & 1;
    const int l15 = lane & 15, lhi = lane >> 4;
    const int swz = (lane & 7) << 4;

    const int gm0 = blockIdx.y * BM, gn0 = blockIdx.x * BN;

    const f16* a_srcs[4]; char* a_ldst[4];
#pragma unroll
    for (int i = 0; i < 4; ++i) {
        const int d = (i * 4 + wid) * 64 + lane;          // [0,1024)
        const int r = d >> 3;
        const int c = (d & 7) ^ (r & 7);
        a_srcs[i] = A + (size_t)(gm0 + r) * 256 + c * 8;
        a_ldst[i] = smem + (i * 4 + wid) * 1024;
    }
    const f16* b_srcs[2]; char* b_ldst[2];
#pragma unroll
    for (int i = 0; i < 2; ++i) {
        const int d = (i * 4 + wid) * 64 + lane;          // [0,512)
        const int rr = d >> 3;
        const int c = (d & 7) ^ (rr & 7);
        b_srcs[i] = B + (size_t)(gn0 + rr) * 256 + c * 8;
        b_ldst[i] = sBm + (i * 4 + wid) * 1024;
    }

    f32x4 acc[4][2];
#pragma unroll
    for (int m = 0; m < 4; ++m)
#pragma unroll
        for (int n = 0; n < 2; ++n) acc[m][n] = (f32x4){0.f, 0.f, 0.f, 0.f};

    for (int kt = 0; kt < 4; ++kt) {
        const int kg = kt * 64;
#pragma unroll
        for (int i = 0; i < 4; ++i) gload16(a_srcs[i] + kg, a_ldst[i]);
#pragma unroll
        for (int i = 0; i < 2; ++i) gload16(b_srcs[i] + kg, b_ldst[i]);
        __syncthreads();
#pragma unroll
        for (int kk = 0; kk < 2; ++kk) {
            const int ko = (kk * 64 + lhi * 16) ^ swz;
            f16x8 af[4], bf[2];
#pragma unroll
            for (int m = 0; m < 4; ++m)
                af[m] = *reinterpret_cast<const f16x8*>(smem + (wm * 64 + m * 16 + l15) * 128 + ko);
#pragma unroll
            for (int n = 0; n < 2; ++n)
                bf[n] = *reinterpret_cast<const f16x8*>(sBm + (wn * 32 + n * 16 + l15) * 128 + ko);
#pragma unroll
            for (int m = 0; m < 4; ++m)
#pragma unroll
                for (int n = 0; n < 2; ++n)
                    acc[m][n] = __builtin_amdgcn_mfma_f32_16x16x32_f16(af[m], bf[n], acc[m][n], 0, 0, 0);
        }
        __syncthreads();
    }

#pragma unroll
    for (int m = 0; m < 4; ++m) {
#pragma unroll
        for (int e = 0; e < 4; ++e) {
            const int b = gm0 + wm * 64 + m * 16 + lhi * 4 + e;
#pragma unroll
            for (int n = 0; n < 2; ++n) {
                const int j = gn0 + wn * 32 + n * 16 + l15;
                if (j < HID) {
                    float v = fmaxf(acc[m][n][e] + bias[j], 0.f);
                    outf[(size_t)b * HP + j] = v;
                    outh[(size_t)b * HP + j] = (f16)v;
                }
            }
        }
    }
}

// ---------------- fused GRU step v7: v6 geometry + R5-proven schedule.
// 384 thr = 6 waves (wave = 64 rows x 16 cols x ALL 3 gates; acc = 48 VGPR; wave-local
// epilogue). Block tile 128 x 48/gate; grid 8bm x 64bn = 512 = 2 blocks/CU (3 waves/SIMD).
// Triple-buffered K=32 slabs (3x17KB), depth-2 prefetch; per slab: counted vmcnt (own
// wave's one-stage load count) BEFORE one s_barrier -> tile globally resident (no race).
// LDS [kg][row][16B] linear layout (R8-verified conflict-free).
__global__ __launch_bounds__(384, 3)
void gru_step(const f16* __restrict__ h16c, float* __restrict__ hf32,
              const f16* __restrict__ whh16,
              const float* __restrict__ xprev,
              const float* __restrict__ Wih, const float* __restrict__ bih,
              const float* __restrict__ bhh,
              f16* __restrict__ h16n)
{
    __shared__ __align__(16) char smem[3 * SLAB];   // 52224 B -> 2 blocks/CU

    const int tid  = threadIdx.x;
    const int lane = tid & 63;
    const int wid  = tid >> 6;          // 0..5
    const int wm   = wid & 1;           // row half: rows [wm*64, wm*64+64)
    const int wsub = wid >> 1;          // col slice: cols [wsub*16, wsub*16+16) per gate
    const int l15 = lane & 15, lhi = lane >> 4;

    // XCD-bijective: xcd = id&7 owns 8 bn x 8 bm (B panels L2-shared within an XCD)
    const int id = blockIdx.x;
    const int xcd = id & 7, local = id >> 3;
    const int bn = xcd * 8 + (local >> 3), bm = local & 7;
    const int gm0 = bm * 128, gn0 = bn * 48;

    // slab slot map (1088 16B slots): A s<512: kg=s>>7,row=s&127 -> LDS s*16;
    // B sb=s-512: kg=sb/144, col=sb%144 (g=col/48, jj=col%48) -> LDS 8192+sb*16.
    // Thread tid owns slots {tid, 384+tid, 768+tid(if tid<320)}. Slab t: src +t*64B.
    const char* src[3];
#pragma unroll
    for (int i = 0; i < 3; ++i) {
        const int s = i * 384 + tid;                 // i==2 used only when tid<320
        if (s < 512) {
            const int kg = s >> 7, row = s & 127;
            src[i] = (const char*)(h16c + (size_t)(gm0 + row) * HP + kg * 8);
        } else {
            const int sb = (s - 512) % 576;          // clamp i==2/tid>=320 (unused) safely
            const int kg = sb / 144, col = sb - kg * 144;
            const int g = col / 48, jj = col - g * 48;
            src[i] = (const char*)(whh16 + (size_t)g * HP * HP + (size_t)(gn0 + jj) * HP + kg * 8);
        }
    }

    f32x4 acc[3][4];
#pragma unroll
    for (int g = 0; g < 3; ++g)
#pragma unroll
        for (int m = 0; m < 4; ++m) acc[g][m] = (f32x4){0.f, 0.f, 0.f, 0.f};

    auto STAGE = [&](int t, char* buf) {
        const uint32_t so = (uint32_t)t * 64u;       // +32 f16 per slab
        gload16(src[0] + so, buf + tid * 16);
        gload16(src[1] + so, buf + (384 + tid) * 16);
        if (tid < 320) gload16(src[2] + so, buf + (768 + tid) * 16);
    };
    auto COMPUTE = [&](const char* buf) {
        const char* ab = buf + lhi * 2048 + (wm * 64 + l15) * 16;
        const char* bb = buf + 8192 + lhi * 2304 + (wsub * 16 + l15) * 16;
        f16x8 af[4], bf[3];
#pragma unroll
        for (int m = 0; m < 4; ++m)
            af[m] = *reinterpret_cast<const f16x8*>(ab + m * 256);
#pragma unroll
        for (int g = 0; g < 3; ++g)
            bf[g] = *reinterpret_cast<const f16x8*>(bb + g * 768);
        __builtin_amdgcn_s_setprio(1);
#pragma unroll
        for (int g = 0; g < 3; ++g)
#pragma unroll
            for (int m = 0; m < 4; ++m)
                acc[g][m] = __builtin_amdgcn_mfma_f32_16x16x32_f16(af[m], bf[g], acc[g][m], 0, 0, 0);
        __builtin_amdgcn_s_setprio(0);
    };

    STAGE(0, smem);
    STAGE(1, smem + SLAB);

    for (int t = 0; t < NSLAB; ++t) {
        // CORRECT order: own-wave counted vmcnt (slab t resident) BEFORE the barrier.
        if (t == NSLAB - 1) asm volatile("s_waitcnt vmcnt(0)" ::: "memory");
        else if (wid < 5)   asm volatile("s_waitcnt vmcnt(3)" ::: "memory");
        else                asm volatile("s_waitcnt vmcnt(2)" ::: "memory");
        __builtin_amdgcn_s_barrier();
        __builtin_amdgcn_sched_barrier(0);
        if (t + 2 < NSLAB) STAGE(t + 2, smem + ((t + 2) % 3) * SLAB);
        COMPUTE(smem + (t % 3) * SLAB);
    }

    // ---- wave-local epilogue: gates + in-place fp32 state update.
    // C/D map: col=lane&15, row=(lane>>4)*4+e
    const int j = gn0 + wsub * 16 + l15;
    if (j < HID) {
        const float* w0 = Wih + (size_t)j * 3;
        const float* w1 = Wih + (size_t)(HID + j) * 3;
        const float* w2 = Wih + (size_t)(2 * HID + j) * 3;
        const float bi0 = bih[j] + bhh[j];
        const float bi1 = bih[HID + j] + bhh[HID + j];
        const float bi2 = bih[2 * HID + j];
        const float bh2 = bhh[2 * HID + j];
#pragma unroll
        for (int m = 0; m < 4; ++m) {
#pragma unroll
            for (int e = 0; e < 4; ++e) {
                const int b = gm0 + wm * 64 + m * 16 + lhi * 4 + e;
                const float x0 = xprev[b * 4 + 0], x1 = xprev[b * 4 + 1], x2 = xprev[b * 4 + 2];
                const float r = sigf(x0 * w0[0] + x1 * w0[1] + x2 * w0[2] + bi0 + acc[0][m][e]);
                const float u = sigf(x0 * w1[0] + x1 * w1[1] + x2 * w1[2] + bi1 + acc[1][m][e]);
                const float nn = tanhf_(x0 * w2[0] + x1 * w2[1] + x2 * w2[2] + bi2
                                        + r * (acc[2][m][e] + bh2));
                const float hp_ = hf32[(size_t)b * HP + j];
                const float hn = (1.f - u) * nn + u * hp_;
                hf32[(size_t)b * HP + j] = hn;
                h16n[(size_t)b * HP + j] = (f16)hn;
            }
        }
    }
}

// ---------------- waypoint readout (R8-passing version): fp32 Wo, block per row
__global__ __launch_bounds__(256) void x_update(const f16* __restrict__ hn,
                                                const float* __restrict__ Wo,
                                                const float* __restrict__ bo,
                                                const float* __restrict__ xp,
                                                float* __restrict__ xn,
                                                float* __restrict__ out, int s)
{
    const int b = blockIdx.x, tid = threadIdx.x;
    float a0 = 0.f, a1 = 0.f, a2 = 0.f;
    for (int ch = tid; ch < 375; ch += 256) {          // 375*8 = 3000 exactly
        const int k = ch * 8;
        f16x8 h8 = *reinterpret_cast<const f16x8*>(hn + (size_t)b * HP + k);
#pragma unroll
        for (int i = 0; i < 8; ++i) {
            float hv = (float)h8[i];
            a0 += hv * Wo[k + i];
            a1 += hv * Wo[HID + k + i];
            a2 += hv * Wo[2 * HID + k + i];
        }
    }
#pragma unroll
    for (int off = 32; off; off >>= 1) {
        a0 += __shfl_down(a0, off);
        a1 += __shfl_down(a1, off);
        a2 += __shfl_down(a2, off);
    }
    __shared__ float red[3][4];
    const int lane = tid & 63, w = tid >> 6;
    if (lane == 0) { red[0][w] = a0; red[1][w] = a1; red[2][w] = a2; }
    __syncthreads();
    if (tid < 3) {
        float sres = red[tid][0] + red[tid][1] + red[tid][2] + red[tid][3];
        float xv = sres + bo[tid] + xp[b * 4 + tid];
        xn[b * 4 + tid] = xv;
        out[((size_t)b * 30 + s) * 3 + tid] = xv;
    }
}

extern "C" void kernel_launch(void* const* d_in, const int* in_sizes, int n_in,
                              void* d_out, int out_size, void* d_ws, size_t ws_size,
                              hipStream_t stream)
{
    (void)in_sizes; (void)n_in; (void)out_size; (void)ws_size;
    const float* z   = (const float*)d_in[0];
    const float* W1  = (const float*)d_in[1];
    const float* b1  = (const float*)d_in[2];
    const float* W2  = (const float*)d_in[3];
    const float* b2  = (const float*)d_in[4];
    const float* W3  = (const float*)d_in[5];
    const float* b3  = (const float*)d_in[6];
    const float* Wih = (const float*)d_in[7];
    const float* bih = (const float*)d_in[8];
    const float* Whh = (const float*)d_in[9];
    const float* bhh = (const float*)d_in[10];
    const float* Wo  = (const float*)d_in[11];
    const float* bo  = (const float*)d_in[12];
    float* out = (float*)d_out;

    char* ws = (char*)d_ws;
    size_t off = 0;
    f16* whh16 = (f16*)(ws + off); off += (size_t)3 * HP * HP * 2;
    f16* h16[2];
    h16[0] = (f16*)(ws + off); off += (size_t)NB * HP * 2;
    h16[1] = (f16*)(ws + off); off += (size_t)NB * HP * 2;
    float* hf  = (float*)(ws + off); off += (size_t)NB * HP * 4;   // in-place fp32 state
    float* h1  = (float*)(ws + off); off += (size_t)NB * 512 * 4;
    float* h2  = (float*)(ws + off); off += (size_t)NB * 256 * 4;
    f16*   h2h = (f16*)(ws + off);   off += (size_t)NB * 256 * 2;
    f16*   w3f16 = (f16*)(ws + off); off += (size_t)HP * 256 * 2;
    float* xb  = (float*)(ws + off); off += (size_t)31 * NB * 4 * 4;

    // zero both f16 h buffers (pad columns must stay 0 as MFMA K inputs) and x_0
    hipMemsetAsync(h16[0], 0, (size_t)2 * NB * HP * 2, stream);
    hipMemsetAsync(xb, 0, (size_t)NB * 4 * 4, stream);

    {
        int s32 = 3 * HP * (HP / 32);
        convert_whh<<<(s32 + 255) / 256, 256, 0, stream>>>(Whh, whh16);
    }
    convert_w3<<<(HP * 32 + 255) / 256, 256, 0, stream>>>(W3, w3f16);

    mlp_layer<<<NB / 4, 256, 0, stream>>>(z,  256, 512, 512, W1, b1, h1, nullptr);
    mlp_layer<<<NB / 4, 256, 0, stream>>>(h1, 512, 256, 256, W2, b2, h2, h2h);
    mlp3_mfma<<<dim3(HP / BN, NB / BM), 256, 0, stream>>>(h2h, w3f16, b3, hf, h16[0]);

    for (int s = 1; s <= 30; ++s) {
        int cur = (s - 1) & 1, nxt = s & 1;
        gru_step<<<512, 384, 0, stream>>>(
            h16[cur], hf, whh16, xb + (size_t)(s - 1) * NB * 4,
            Wih, bih, bhh, h16[nxt]);
        x_update<<<NB, 256, 0, stream>>>(h16[nxt], Wo, bo,
            xb + (size_t)(s - 1) * NB * 4, xb + (size_t)s * NB * 4, out, s - 1);
    }
}

// Round 11
// 2171.049 us; speedup vs baseline: 2.0175x; 2.0175x over previous
//
#include <hip/hip_runtime.h>
#include <cstdint>
#include <cstddef>

#define HID 3000
#define HP  3072          // padded hidden (2^10 * 3)
#define NB  1024          // batch
#define BM  128           // mlp3 tile
#define BN  64            // mlp3 per-tile N
#define KT  48            // HP/64 K-steps for gru
#define BUFSZ 51200       // gru LDS buffer: A 256x64 f16 (32KB) + B 144x64 f16 (18KB)
#define PLANE 13312       // 256*52 f32 per gate plane (epilogue)

typedef _Float16 f16;
typedef _Float16 f16x8 __attribute__((ext_vector_type(8)));
typedef float    f32x4 __attribute__((ext_vector_type(4)));

__device__ __forceinline__ float sigf(float v)  { return 1.0f / (1.0f + __expf(-v)); }
__device__ __forceinline__ float tanhf_(float v){ return 2.0f / (1.0f + __expf(-2.0f * v)) - 1.0f; }

// async global->LDS, 16B per lane. LDS dest = wave-uniform base + lane*16 (linear).
__device__ __forceinline__ void gload16(const void* g, void* l) {
    __builtin_amdgcn_global_load_lds((const __attribute__((address_space(1))) void*)g,
                                     (__attribute__((address_space(3))) void*)l, 16, 0, 0);
}

// ---------------- Whh fp32 -> fp16, padded [3][HP][HP]; 128B-in/64B-out per thread
__global__ __launch_bounds__(256) void convert_whh(const float* __restrict__ whh,
                                                   f16* __restrict__ whh16)
{
    const int S32 = 3 * HP * (HP / 32);
    int t = blockIdx.x * 256 + threadIdx.x;
    if (t >= S32) return;
    const int c32 = (t % (HP / 32)) * 32;
    const int rr  = (t / (HP / 32)) % HP;
    const int g   = t / ((HP / 32) * HP);
    f16* dst = whh16 + ((size_t)g * HP + rr) * HP + c32;
    if (rr < HID && c32 + 32 <= HID) {
        const float* src = whh + (size_t)(g * HID + rr) * HID + c32;
#pragma unroll
        for (int u = 0; u < 4; ++u) {
            float4 lo = *reinterpret_cast<const float4*>(src + u * 8);
            float4 hi = *reinterpret_cast<const float4*>(src + u * 8 + 4);
            f16x8 v;
            v[0] = (f16)lo.x; v[1] = (f16)lo.y; v[2] = (f16)lo.z; v[3] = (f16)lo.w;
            v[4] = (f16)hi.x; v[5] = (f16)hi.y; v[6] = (f16)hi.z; v[7] = (f16)hi.w;
            *reinterpret_cast<f16x8*>(dst + u * 8) = v;
        }
    } else {
#pragma unroll
        for (int u = 0; u < 4; ++u) {
            f16x8 v;
#pragma unroll
            for (int k = 0; k < 8; ++k) {
                const int cc = c32 + u * 8 + k;
                v[k] = (rr < HID && cc < HID) ? (f16)whh[(size_t)(g * HID + rr) * HID + cc]
                                              : (f16)0.0f;
            }
            *reinterpret_cast<f16x8*>(dst + u * 8) = v;
        }
    }
}

// ---------------- W3 fp32 [3000][256] -> f16 [HP][256], zero-padded rows
__global__ __launch_bounds__(256) void convert_w3(const float* __restrict__ w,
                                                  f16* __restrict__ w16)
{
    int t = blockIdx.x * 256 + threadIdx.x;      // HP * 32 slots of 8
    if (t >= HP * 32) return;
    int rr = t >> 5, c8 = (t & 31) * 8;
    f16x8 v;
    if (rr < HID) {
        const float* src = w + (size_t)rr * 256 + c8;
        float4 lo = *reinterpret_cast<const float4*>(src);
        float4 hi = *reinterpret_cast<const float4*>(src + 4);
        v[0] = (f16)lo.x; v[1] = (f16)lo.y; v[2] = (f16)lo.z; v[3] = (f16)lo.w;
        v[4] = (f16)hi.x; v[5] = (f16)hi.y; v[6] = (f16)hi.z; v[7] = (f16)hi.w;
    } else {
#pragma unroll
        for (int i = 0; i < 8; ++i) v[i] = (f16)0.0f;
    }
    *reinterpret_cast<f16x8*>(w16 + (size_t)rr * 256 + c8) = v;
}

// ---------------- small fp32 MLP layer: out = relu(A @ W^T + b), optional f16 copy
__global__ __launch_bounds__(256) void mlp_layer(const float* __restrict__ A, int K, int N, int ldo,
                                                 const float* __restrict__ W,
                                                 const float* __restrict__ bias,
                                                 float* __restrict__ outf, f16* __restrict__ outh)
{
    __shared__ float sA[4 * 512];
    const int b0 = blockIdx.x * 4;
    for (int idx = threadIdx.x; idx < 4 * K; idx += 256)
        sA[idx] = A[(size_t)b0 * K + idx];
    __syncthreads();
    for (int n = threadIdx.x; n < ldo; n += 256) {
        float acc[4] = {0.f, 0.f, 0.f, 0.f};
        if (n < N) {
            const float4* wr = reinterpret_cast<const float4*>(W + (size_t)n * K);
            for (int kk = 0; kk < (K >> 2); ++kk) {
                float4 w = wr[kk];
#pragma unroll
                for (int r = 0; r < 4; ++r) {
                    const float* ar = sA + r * K + kk * 4;
                    acc[r] += ar[0] * w.x + ar[1] * w.y + ar[2] * w.z + ar[3] * w.w;
                }
            }
            float bv = bias[n];
#pragma unroll
            for (int r = 0; r < 4; ++r) acc[r] = fmaxf(acc[r] + bv, 0.f);
        }
#pragma unroll
        for (int r = 0; r < 4; ++r) {
            outf[(size_t)(b0 + r) * ldo + n] = acc[r];
            if (outh) outh[(size_t)(b0 + r) * ldo + n] = (f16)acc[r];
        }
    }
}

// ---------------- W3 layer via MFMA: out = relu(A @ B^T + b3); A [NB][256] f16, B [HP][256] f16
__global__ __launch_bounds__(256, 2)
void mlp3_mfma(const f16* __restrict__ A, const f16* __restrict__ B,
               const float* __restrict__ bias,
               float* __restrict__ outf, f16* __restrict__ outh)
{
    __shared__ __align__(16) char smem[24576];   // sA 16KB | sB 8KB
    char* sBm = smem + 16384;

    const int tid  = threadIdx.x;
    const int lane = tid & 63;
    const int wid  = tid >> 6;
    const int wm = wid >> 1, wn = wid & 1;
    const int l15 = lane & 15, lhi = lane >> 4;
    const int swz = (lane & 7) << 4;

    const int gm0 = blockIdx.y * BM, gn0 = blockIdx.x * BN;

    const f16* a_srcs[4]; char* a_ldst[4];
#pragma unroll
    for (int i = 0; i < 4; ++i) {
        const int d = (i * 4 + wid) * 64 + lane;          // [0,1024)
        const int r = d >> 3;
        const int c = (d & 7) ^ (r & 7);
        a_srcs[i] = A + (size_t)(gm0 + r) * 256 + c * 8;
        a_ldst[i] = smem + (i * 4 + wid) * 1024;
    }
    const f16* b_srcs[2]; char* b_ldst[2];
#pragma unroll
    for (int i = 0; i < 2; ++i) {
        const int d = (i * 4 + wid) * 64 + lane;          // [0,512)
        const int rr = d >> 3;
        const int c = (d & 7) ^ (rr & 7);
        b_srcs[i] = B + (size_t)(gn0 + rr) * 256 + c * 8;
        b_ldst[i] = sBm + (i * 4 + wid) * 1024;
    }

    f32x4 acc[4][2];
#pragma unroll
    for (int m = 0; m < 4; ++m)
#pragma unroll
        for (int n = 0; n < 2; ++n) acc[m][n] = (f32x4){0.f, 0.f, 0.f, 0.f};

    for (int kt = 0; kt < 4; ++kt) {
        const int kg = kt * 64;
#pragma unroll
        for (int i = 0; i < 4; ++i) gload16(a_srcs[i] + kg, a_ldst[i]);
#pragma unroll
        for (int i = 0; i < 2; ++i) gload16(b_srcs[i] + kg, b_ldst[i]);
        __syncthreads();
#pragma unroll
        for (int kk = 0; kk < 2; ++kk) {
            const int ko = (kk * 64 + lhi * 16) ^ swz;
            f16x8 af[4], bf[2];
#pragma unroll
            for (int m = 0; m < 4; ++m)
                af[m] = *reinterpret_cast<const f16x8*>(smem + (wm * 64 + m * 16 + l15) * 128 + ko);
#pragma unroll
            for (int n = 0; n < 2; ++n)
                bf[n] = *reinterpret_cast<const f16x8*>(sBm + (wn * 32 + n * 16 + l15) * 128 + ko);
#pragma unroll
            for (int m = 0; m < 4; ++m)
#pragma unroll
                for (int n = 0; n < 2; ++n)
                    acc[m][n] = __builtin_amdgcn_mfma_f32_16x16x32_f16(af[m], bf[n], acc[m][n], 0, 0, 0);
        }
        __syncthreads();
    }

#pragma unroll
    for (int m = 0; m < 4; ++m) {
#pragma unroll
        for (int e = 0; e < 4; ++e) {
            const int b = gm0 + wm * 64 + m * 16 + lhi * 4 + e;
#pragma unroll
            for (int n = 0; n < 2; ++n) {
                const int j = gn0 + wn * 32 + n * 16 + l15;
                if (j < HID) {
                    float v = fmaxf(acc[m][n][e] + bias[j], 0.f);
                    outf[(size_t)b * HP + j] = v;
                    outh[(size_t)b * HP + j] = (f16)v;
                }
            }
        }
    }
}

// ---------------- fused GRU step (round-5 proven): 256x144 tile, 12 waves (4M x 3N=gate),
// grid 256 = 1/CU. Triple-buffered LDS, depth-2 prefetch, ONE barrier + counted vmcnt
// per K-step, LDS-plane gate exchange epilogue.
__global__ __launch_bounds__(768, 3)
void gru_step(const f16* __restrict__ h16c, float* __restrict__ hf32,
              const f16* __restrict__ whh16,
              const float* __restrict__ xprev,
              const float* __restrict__ Wih, const float* __restrict__ bih,
              const float* __restrict__ bhh,
              f16* __restrict__ h16n)
{
    __shared__ __align__(16) char smem[159744];  // 3 x 51200 bufs; reused as 3 x 53248 planes

    const int tid  = threadIdx.x;
    const int lane = tid & 63;
    const int wid  = tid >> 6;          // 0..11
    const int wm   = wid & 3;           // row group: rows [wm*64, wm*64+64)
    const int wn   = wid >> 2;          // gate 0..2
    const int l15 = lane & 15, lhi = lane >> 4;
    const int swz = (lane & 7) << 4;

    // XCD-bijective: xcd owns bn in [8*xcd, 8*xcd+8); the 4 bm-blocks of a bn share one XCD.
    const int id = blockIdx.x;
    const int xcd = id & 7, local = id >> 3;
    const int bn = xcd * 8 + (local >> 2), bm = local & 3;
    const int gm0 = bm * 256, gn0 = bn * 48;

    // staging: slots of 16B. A: 0..2047 (256 rows x 8), B: 2048..3199 (144 rows x 8).
    // LDS dest linear (slot*16); inverse XOR-swizzle applied to the GLOBAL source column.
    const f16* srcs[5];
#pragma unroll
    for (int i = 0; i < 4; ++i) {
        const int s = i * 768 + tid;
        if (s < 2048) {
            const int r = s >> 3;
            const int c = (s & 7) ^ (r & 7);
            srcs[i] = h16c + (size_t)(gm0 + r) * HP + c * 8;
        } else {
            const int sb = s - 2048;
            const int rr = sb >> 3;                  // g*48 + j'
            const int g = rr / 48, jj = rr - g * 48;
            const int c = (sb & 7) ^ (rr & 7);
            srcs[i] = whh16 + (size_t)g * HP * HP + (size_t)(gn0 + jj) * HP + c * 8;
        }
    }
    {
        const int sb = 1024 + tid;                   // used only when tid < 128
        const int rr = sb >> 3;                      // 128..143 -> gate 2
        const int g = rr / 48, jj = rr - g * 48;
        const int c = (sb & 7) ^ (rr & 7);
        srcs[4] = whh16 + (size_t)g * HP * HP + (size_t)(gn0 + jj) * HP + c * 8;
    }

    f32x4 acc[4][3];
#pragma unroll
    for (int m = 0; m < 4; ++m)
#pragma unroll
        for (int n = 0; n < 3; ++n) acc[m][n] = (f32x4){0.f, 0.f, 0.f, 0.f};

    // stage: waves 0,1 issue 5 load-instrs/tile, waves 2..11 issue 4.
    auto STAGE = [&](int kt, char* bufc) {
        const int ko = kt * 64;
#pragma unroll
        for (int i = 0; i < 4; ++i)
            gload16(srcs[i] + ko, bufc + (i * 12 + wid) * 1024);
        if (tid < 128) gload16(srcs[4] + ko, bufc + (48 + wid) * 1024);
    };
    auto COMPUTE = [&](const char* bufc) {
#pragma unroll
        for (int kk = 0; kk < 2; ++kk) {
            const int ko = (kk * 64 + lhi * 16) ^ swz;
            f16x8 af[4], bf[3];
#pragma unroll
            for (int m = 0; m < 4; ++m)
                af[m] = *reinterpret_cast<const f16x8*>(bufc + (wm * 64 + m * 16 + l15) * 128 + ko);
#pragma unroll
            for (int n = 0; n < 3; ++n)
                bf[n] = *reinterpret_cast<const f16x8*>(bufc + 32768 + (wn * 48 + n * 16 + l15) * 128 + ko);
            __builtin_amdgcn_s_setprio(1);
#pragma unroll
            for (int m = 0; m < 4; ++m)
#pragma unroll
                for (int n = 0; n < 3; ++n)
                    acc[m][n] = __builtin_amdgcn_mfma_f32_16x16x32_f16(af[m], bf[n], acc[m][n], 0, 0, 0);
            __builtin_amdgcn_s_setprio(0);
        }
    };

    STAGE(0, smem);
    STAGE(1, smem + BUFSZ);

    int cur = 0;
    for (int t = 0; t < KT; ++t) {
        // counted vmcnt: allow tile t+1's loads (own wave's count) to stay in flight.
        if (t == KT - 1)      asm volatile("s_waitcnt vmcnt(0)" ::: "memory");
        else if (wid < 2)     asm volatile("s_waitcnt vmcnt(5)" ::: "memory");
        else                  asm volatile("s_waitcnt vmcnt(4)" ::: "memory");
        __builtin_amdgcn_s_barrier();
        __builtin_amdgcn_sched_barrier(0);
        if (t + 2 < KT) {
            int b2 = cur + 2; if (b2 >= 3) b2 -= 3;
            STAGE(t + 2, smem + b2 * BUFSZ);
        }
        COMPUTE(smem + cur * BUFSZ);
        ++cur; if (cur == 3) cur = 0;
    }

    // ---- epilogue: exchange gates via LDS planes, then all threads do gate math
    __syncthreads();
    float* planes = reinterpret_cast<float*>(smem);
    {
        float* myplane = planes + wn * PLANE;
#pragma unroll
        for (int m = 0; m < 4; ++m)
#pragma unroll
            for (int n = 0; n < 3; ++n)
#pragma unroll
                for (int e = 0; e < 4; ++e)
                    myplane[(wm * 64 + m * 16 + lhi * 4 + e) * 52 + n * 16 + l15] = acc[m][n][e];
    }
    __syncthreads();

#pragma unroll
    for (int cc = 0; cc < 2; ++cc) {
        const int c = tid + cc * 768;                 // 1536 chunks of 8
        const int row = c / 6;
        const int coff = (c - row * 6) * 8;
        const int b = gm0 + row;
        const int jb = gn0 + coff;
        if (jb >= HID) continue;
        const float x0 = xprev[b * 4 + 0], x1 = xprev[b * 4 + 1], x2 = xprev[b * 4 + 2];
        const int pb = row * 52 + coff;
        const int nv = (jb + 8 <= HID) ? 8 : (HID - jb);
        float hn[8];
#pragma unroll
        for (int i = 0; i < 8; ++i) {
            if (i < nv) {
                const int j = jb + i;
                const float g0 = planes[pb + i];
                const float g1 = planes[PLANE + pb + i];
                const float g2 = planes[2 * PLANE + pb + i];
                const float* w0 = Wih + (size_t)j * 3;
                const float* w1 = Wih + (size_t)(HID + j) * 3;
                const float* w2 = Wih + (size_t)(2 * HID + j) * 3;
                const float gi0 = x0 * w0[0] + x1 * w0[1] + x2 * w0[2] + bih[j];
                const float gi1 = x0 * w1[0] + x1 * w1[1] + x2 * w1[2] + bih[HID + j];
                const float gi2 = x0 * w2[0] + x1 * w2[1] + x2 * w2[2] + bih[2 * HID + j];
                const float r = sigf(gi0 + g0 + bhh[j]);
                const float u = sigf(gi1 + g1 + bhh[HID + j]);
                const float nn = tanhf_(gi2 + r * (g2 + bhh[2 * HID + j]));
                const float hp_ = hf32[(size_t)b * HP + j];
                hn[i] = (1.f - u) * nn + u * hp_;
            }
        }
        if (nv == 8) {
            f16x8 hv;
#pragma unroll
            for (int i = 0; i < 8; ++i) hv[i] = (f16)hn[i];
            *reinterpret_cast<f16x8*>(h16n + (size_t)b * HP + jb) = hv;
            float4 f0 = {hn[0], hn[1], hn[2], hn[3]};
            float4 f1 = {hn[4], hn[5], hn[6], hn[7]};
            *reinterpret_cast<float4*>(hf32 + (size_t)b * HP + jb) = f0;
            *reinterpret_cast<float4*>(hf32 + (size_t)b * HP + jb + 4) = f1;
        } else {
            for (int i = 0; i < nv; ++i) {
                hf32[(size_t)b * HP + jb + i] = hn[i];
                h16n[(size_t)b * HP + jb + i] = (f16)hn[i];
            }
        }
    }
}

// ---------------- waypoint readout: wave-per-row (4 rows/block), fp32 Wo
__global__ __launch_bounds__(256) void x_update(const f16* __restrict__ hn,
                                                const float* __restrict__ Wo,
                                                const float* __restrict__ bo,
                                                const float* __restrict__ xp,
                                                float* __restrict__ xn,
                                                float* __restrict__ out, int s)
{
    const int w = threadIdx.x >> 6, lane = threadIdx.x & 63;
    const int b = blockIdx.x * 4 + w;
    float a0 = 0.f, a1 = 0.f, a2 = 0.f;
#pragma unroll
    for (int i = 0; i < 6; ++i) {
        const int ch = i * 64 + lane;
        if (ch < 375) {                               // 375*8 = 3000 exactly
            const int k = ch * 8;
            f16x8 h8 = *reinterpret_cast<const f16x8*>(hn + (size_t)b * HP + k);
#pragma unroll
            for (int q = 0; q < 8; ++q) {
                const float hv = (float)h8[q];
                a0 += hv * Wo[k + q];
                a1 += hv * Wo[HID + k + q];
                a2 += hv * Wo[2 * HID + k + q];
            }
        }
    }
#pragma unroll
    for (int off = 32; off; off >>= 1) {
        a0 += __shfl_down(a0, off);
        a1 += __shfl_down(a1, off);
        a2 += __shfl_down(a2, off);
    }
    if (lane == 0) {
        const float r0 = a0 + bo[0] + xp[b * 4 + 0];
        const float r1 = a1 + bo[1] + xp[b * 4 + 1];
        const float r2 = a2 + bo[2] + xp[b * 4 + 2];
        xn[b * 4 + 0] = r0; xn[b * 4 + 1] = r1; xn[b * 4 + 2] = r2;
        float* o = out + ((size_t)b * 30 + s) * 3;
        o[0] = r0; o[1] = r1; o[2] = r2;
    }
}

extern "C" void kernel_launch(void* const* d_in, const int* in_sizes, int n_in,
                              void* d_out, int out_size, void* d_ws, size_t ws_size,
                              hipStream_t stream)
{
    (void)in_sizes; (void)n_in; (void)out_size; (void)ws_size;
    const float* z   = (const float*)d_in[0];
    const float* W1  = (const float*)d_in[1];
    const float* b1  = (const float*)d_in[2];
    const float* W2  = (const float*)d_in[3];
    const float* b2  = (const float*)d_in[4];
    const float* W3  = (const float*)d_in[5];
    const float* b3  = (const float*)d_in[6];
    const float* Wih = (const float*)d_in[7];
    const float* bih = (const float*)d_in[8];
    const float* Whh = (const float*)d_in[9];
    const float* bhh = (const float*)d_in[10];
    const float* Wo  = (const float*)d_in[11];
    const float* bo  = (const float*)d_in[12];
    float* out = (float*)d_out;

    char* ws = (char*)d_ws;
    size_t off = 0;
    f16* whh16 = (f16*)(ws + off); off += (size_t)3 * HP * HP * 2;
    f16* h16[2];
    h16[0] = (f16*)(ws + off); off += (size_t)NB * HP * 2;
    h16[1] = (f16*)(ws + off); off += (size_t)NB * HP * 2;
    float* hf  = (float*)(ws + off); off += (size_t)NB * HP * 4;   // in-place fp32 state
    float* h1  = (float*)(ws + off); off += (size_t)NB * 512 * 4;
    float* h2  = (float*)(ws + off); off += (size_t)NB * 256 * 4;
    f16*   h2h = (f16*)(ws + off);   off += (size_t)NB * 256 * 2;
    f16*   w3f16 = (f16*)(ws + off); off += (size_t)HP * 256 * 2;
    float* xb  = (float*)(ws + off); off += (size_t)31 * NB * 4 * 4;

    // zero both f16 h buffers (pad columns must stay 0 as MFMA K inputs) and x_0
    hipMemsetAsync(h16[0], 0, (size_t)2 * NB * HP * 2, stream);
    hipMemsetAsync(xb, 0, (size_t)NB * 4 * 4, stream);

    {
        int s32 = 3 * HP * (HP / 32);
        convert_whh<<<(s32 + 255) / 256, 256, 0, stream>>>(Whh, whh16);
    }
    convert_w3<<<(HP * 32 + 255) / 256, 256, 0, stream>>>(W3, w3f16);

    mlp_layer<<<NB / 4, 256, 0, stream>>>(z,  256, 512, 512, W1, b1, h1, nullptr);
    mlp_layer<<<NB / 4, 256, 0, stream>>>(h1, 512, 256, 256, W2, b2, h2, h2h);
    mlp3_mfma<<<dim3(HP / BN, NB / BM), 256, 0, stream>>>(h2h, w3f16, b3, hf, h16[0]);

    for (int s = 1; s <= 30; ++s) {
        int cur = (s - 1) & 1, nxt = s & 1;
        gru_step<<<256, 768, 0, stream>>>(
            h16[cur], hf, whh16, xb + (size_t)(s - 1) * NB * 4,
            Wih, bih, bhh, h16[nxt]);
        x_update<<<NB / 4, 256, 0, stream>>>(h16[nxt], Wo, bo,
            xb + (size_t)(s - 1) * NB * 4, xb + (size_t)s * NB * 4, out, s - 1);
    }
}

// Round 12
// 2140.582 us; speedup vs baseline: 2.0462x; 1.0142x over previous
//
#include <hip/hip_runtime.h>
#include <cstdint>
#include <cstddef>

#define HID 3000
#define HP  3072          // padded hidden (2^10 * 3)
#define NB  1024          // batch
#define BM  128           // mlp3 tile
#define BN  64            // mlp3 per-tile N
#define KT  48            // HP/64 K-steps for gru
#define BUFSZ 51200       // gru LDS buffer: A 256x64 f16 (32KB) + B 144x64 f16 (18KB)
#define PLANE 13312       // 256*52 f32 per gate plane (epilogue)

typedef _Float16 f16;
typedef _Float16 f16x8 __attribute__((ext_vector_type(8)));
typedef float    f32x4 __attribute__((ext_vector_type(4)));

__device__ __forceinline__ float sigf(float v)  { return 1.0f / (1.0f + __expf(-v)); }
__device__ __forceinline__ float tanhf_(float v){ return 2.0f / (1.0f + __expf(-2.0f * v)) - 1.0f; }

// async global->LDS, 16B per lane. LDS dest = wave-uniform base + lane*16 (linear).
__device__ __forceinline__ void gload16(const void* g, void* l) {
    __builtin_amdgcn_global_load_lds((const __attribute__((address_space(1))) void*)g,
                                     (__attribute__((address_space(3))) void*)l, 16, 0, 0);
}

// ---------------- Whh fp32 -> fp16, padded [3][HP][HP]; 128B-in/64B-out per thread
__global__ __launch_bounds__(256) void convert_whh(const float* __restrict__ whh,
                                                   f16* __restrict__ whh16)
{
    const int S32 = 3 * HP * (HP / 32);
    int t = blockIdx.x * 256 + threadIdx.x;
    if (t >= S32) return;
    const int c32 = (t % (HP / 32)) * 32;
    const int rr  = (t / (HP / 32)) % HP;
    const int g   = t / ((HP / 32) * HP);
    f16* dst = whh16 + ((size_t)g * HP + rr) * HP + c32;
    if (rr < HID && c32 + 32 <= HID) {
        const float* src = whh + (size_t)(g * HID + rr) * HID + c32;
#pragma unroll
        for (int u = 0; u < 4; ++u) {
            float4 lo = *reinterpret_cast<const float4*>(src + u * 8);
            float4 hi = *reinterpret_cast<const float4*>(src + u * 8 + 4);
            f16x8 v;
            v[0] = (f16)lo.x; v[1] = (f16)lo.y; v[2] = (f16)lo.z; v[3] = (f16)lo.w;
            v[4] = (f16)hi.x; v[5] = (f16)hi.y; v[6] = (f16)hi.z; v[7] = (f16)hi.w;
            *reinterpret_cast<f16x8*>(dst + u * 8) = v;
        }
    } else {
#pragma unroll
        for (int u = 0; u < 4; ++u) {
            f16x8 v;
#pragma unroll
            for (int k = 0; k < 8; ++k) {
                const int cc = c32 + u * 8 + k;
                v[k] = (rr < HID && cc < HID) ? (f16)whh[(size_t)(g * HID + rr) * HID + cc]
                                              : (f16)0.0f;
            }
            *reinterpret_cast<f16x8*>(dst + u * 8) = v;
        }
    }
}

// ---------------- W3 fp32 [3000][256] -> f16 [HP][256], zero-padded rows
__global__ __launch_bounds__(256) void convert_w3(const float* __restrict__ w,
                                                  f16* __restrict__ w16)
{
    int t = blockIdx.x * 256 + threadIdx.x;      // HP * 32 slots of 8
    if (t >= HP * 32) return;
    int rr = t >> 5, c8 = (t & 31) * 8;
    f16x8 v;
    if (rr < HID) {
        const float* src = w + (size_t)rr * 256 + c8;
        float4 lo = *reinterpret_cast<const float4*>(src);
        float4 hi = *reinterpret_cast<const float4*>(src + 4);
        v[0] = (f16)lo.x; v[1] = (f16)lo.y; v[2] = (f16)lo.z; v[3] = (f16)lo.w;
        v[4] = (f16)hi.x; v[5] = (f16)hi.y; v[6] = (f16)hi.z; v[7] = (f16)hi.w;
    } else {
#pragma unroll
        for (int i = 0; i < 8; ++i) v[i] = (f16)0.0f;
    }
    *reinterpret_cast<f16x8*>(w16 + (size_t)rr * 256 + c8) = v;
}

// ---------------- small fp32 MLP layer: out = relu(A @ W^T + b), optional f16 copy
__global__ __launch_bounds__(256) void mlp_layer(const float* __restrict__ A, int K, int N, int ldo,
                                                 const float* __restrict__ W,
                                                 const float* __restrict__ bias,
                                                 float* __restrict__ outf, f16* __restrict__ outh)
{
    __shared__ float sA[4 * 512];
    const int b0 = blockIdx.x * 4;
    for (int idx = threadIdx.x; idx < 4 * K; idx += 256)
        sA[idx] = A[(size_t)b0 * K + idx];
    __syncthreads();
    for (int n = threadIdx.x; n < ldo; n += 256) {
        float acc[4] = {0.f, 0.f, 0.f, 0.f};
        if (n < N) {
            const float4* wr = reinterpret_cast<const float4*>(W + (size_t)n * K);
            for (int kk = 0; kk < (K >> 2); ++kk) {
                float4 w = wr[kk];
#pragma unroll
                for (int r = 0; r < 4; ++r) {
                    const float* ar = sA + r * K + kk * 4;
                    acc[r] += ar[0] * w.x + ar[1] * w.y + ar[2] * w.z + ar[3] * w.w;
                }
            }
            float bv = bias[n];
#pragma unroll
            for (int r = 0; r < 4; ++r) acc[r] = fmaxf(acc[r] + bv, 0.f);
        }
#pragma unroll
        for (int r = 0; r < 4; ++r) {
            outf[(size_t)(b0 + r) * ldo + n] = acc[r];
            if (outh) outh[(size_t)(b0 + r) * ldo + n] = (f16)acc[r];
        }
    }
}

// ---------------- W3 layer via MFMA: out = relu(A @ B^T + b3); A [NB][256] f16, B [HP][256] f16
__global__ __launch_bounds__(256, 2)
void mlp3_mfma(const f16* __restrict__ A, const f16* __restrict__ B,
               const float* __restrict__ bias,
               float* __restrict__ outf, f16* __restrict__ outh)
{
    __shared__ __align__(16) char smem[24576];   // sA 16KB | sB 8KB
    char* sBm = smem + 16384;

    const int tid  = threadIdx.x;
    const int lane = tid & 63;
    const int wid  = tid >> 6;
    const int wm = wid >> 1, wn = wid & 1;
    const int l15 = lane & 15, lhi = lane >> 4;
    const int swz = (lane & 7) << 4;

    const int gm0 = blockIdx.y * BM, gn0 = blockIdx.x * BN;

    const f16* a_srcs[4]; char* a_ldst[4];
#pragma unroll
    for (int i = 0; i < 4; ++i) {
        const int d = (i * 4 + wid) * 64 + lane;          // [0,1024)
        const int r = d >> 3;
        const int c = (d & 7) ^ (r & 7);
        a_srcs[i] = A + (size_t)(gm0 + r) * 256 + c * 8;
        a_ldst[i] = smem + (i * 4 + wid) * 1024;
    }
    const f16* b_srcs[2]; char* b_ldst[2];
#pragma unroll
    for (int i = 0; i < 2; ++i) {
        const int d = (i * 4 + wid) * 64 + lane;          // [0,512)
        const int rr = d >> 3;
        const int c = (d & 7) ^ (rr & 7);
        b_srcs[i] = B + (size_t)(gn0 + rr) * 256 + c * 8;
        b_ldst[i] = sBm + (i * 4 + wid) * 1024;
    }

    f32x4 acc[4][2];
#pragma unroll
    for (int m = 0; m < 4; ++m)
#pragma unroll
        for (int n = 0; n < 2; ++n) acc[m][n] = (f32x4){0.f, 0.f, 0.f, 0.f};

    for (int kt = 0; kt < 4; ++kt) {
        const int kg = kt * 64;
#pragma unroll
        for (int i = 0; i < 4; ++i) gload16(a_srcs[i] + kg, a_ldst[i]);
#pragma unroll
        for (int i = 0; i < 2; ++i) gload16(b_srcs[i] + kg, b_ldst[i]);
        __syncthreads();
#pragma unroll
        for (int kk = 0; kk < 2; ++kk) {
            const int ko = (kk * 64 + lhi * 16) ^ swz;
            f16x8 af[4], bf[2];
#pragma unroll
            for (int m = 0; m < 4; ++m)
                af[m] = *reinterpret_cast<const f16x8*>(smem + (wm * 64 + m * 16 + l15) * 128 + ko);
#pragma unroll
            for (int n = 0; n < 2; ++n)
                bf[n] = *reinterpret_cast<const f16x8*>(sBm + (wn * 32 + n * 16 + l15) * 128 + ko);
#pragma unroll
            for (int m = 0; m < 4; ++m)
#pragma unroll
                for (int n = 0; n < 2; ++n)
                    acc[m][n] = __builtin_amdgcn_mfma_f32_16x16x32_f16(af[m], bf[n], acc[m][n], 0, 0, 0);
        }
        __syncthreads();
    }

#pragma unroll
    for (int m = 0; m < 4; ++m) {
#pragma unroll
        for (int e = 0; e < 4; ++e) {
            const int b = gm0 + wm * 64 + m * 16 + lhi * 4 + e;
#pragma unroll
            for (int n = 0; n < 2; ++n) {
                const int j = gn0 + wn * 32 + n * 16 + l15;
                if (j < HID) {
                    float v = fmaxf(acc[m][n][e] + bias[j], 0.f);
                    outf[(size_t)b * HP + j] = v;
                    outh[(size_t)b * HP + j] = (f16)v;
                }
            }
        }
    }
}

// ---------------- fused GRU step (R5 skeleton + hoisted-read single-cluster K-step):
// 256x144 tile, 12 waves (4M x 3N=gate), grid 256 = 1/CU. Triple-buffered LDS, depth-2
// prefetch, ONE barrier + counted vmcnt per K-step. Per interval: 14 ds_read (both kk
// halves) -> STAGE issue -> 24-MFMA setprio cluster. LDS-plane gate exchange epilogue.
__global__ __launch_bounds__(768, 3)
void gru_step(const f16* __restrict__ h16c, float* __restrict__ hf32,
              const f16* __restrict__ whh16,
              const float* __restrict__ xprev,
              const float* __restrict__ Wih, const float* __restrict__ bih,
              const float* __restrict__ bhh,
              f16* __restrict__ h16n)
{
    __shared__ __align__(16) char smem[159744];  // 3 x 51200 bufs; reused as 3 x 53248 planes

    const int tid  = threadIdx.x;
    const int lane = tid & 63;
    const int wid  = tid >> 6;          // 0..11
    const int wm   = wid & 3;           // row group: rows [wm*64, wm*64+64)
    const int wn   = wid >> 2;          // gate 0..2
    const int l15 = lane & 15, lhi = lane >> 4;
    const int swz = (lane & 7) << 4;

    // XCD-bijective: xcd owns bn in [8*xcd, 8*xcd+8); the 4 bm-blocks of a bn share one XCD.
    const int id = blockIdx.x;
    const int xcd = id & 7, local = id >> 3;
    const int bn = xcd * 8 + (local >> 2), bm = local & 3;
    const int gm0 = bm * 256, gn0 = bn * 48;

    // staging: slots of 16B. A: 0..2047 (256 rows x 8), B: 2048..3199 (144 rows x 8).
    // LDS dest linear (slot*16); inverse XOR-swizzle applied to the GLOBAL source column.
    const f16* srcs[5];
#pragma unroll
    for (int i = 0; i < 4; ++i) {
        const int s = i * 768 + tid;
        if (s < 2048) {
            const int r = s >> 3;
            const int c = (s & 7) ^ (r & 7);
            srcs[i] = h16c + (size_t)(gm0 + r) * HP + c * 8;
        } else {
            const int sb = s - 2048;
            const int rr = sb >> 3;                  // g*48 + j'
            const int g = rr / 48, jj = rr - g * 48;
            const int c = (sb & 7) ^ (rr & 7);
            srcs[i] = whh16 + (size_t)g * HP * HP + (size_t)(gn0 + jj) * HP + c * 8;
        }
    }
    {
        const int sb = 1024 + tid;                   // used only when tid < 128
        const int rr = sb >> 3;                      // 128..143 -> gate 2
        const int g = rr / 48, jj = rr - g * 48;
        const int c = (sb & 7) ^ (rr & 7);
        srcs[4] = whh16 + (size_t)g * HP * HP + (size_t)(gn0 + jj) * HP + c * 8;
    }

    f32x4 acc[4][3];
#pragma unroll
    for (int m = 0; m < 4; ++m)
#pragma unroll
        for (int n = 0; n < 3; ++n) acc[m][n] = (f32x4){0.f, 0.f, 0.f, 0.f};

    // stage: waves 0,1 issue 5 load-instrs/tile, waves 2..11 issue 4.
    auto STAGE = [&](int kt, char* bufc) {
        const int ko = kt * 64;
#pragma unroll
        for (int i = 0; i < 4; ++i)
            gload16(srcs[i] + ko, bufc + (i * 12 + wid) * 1024);
        if (tid < 128) gload16(srcs[4] + ko, bufc + (48 + wid) * 1024);
    };

    STAGE(0, smem);
    STAGE(1, smem + BUFSZ);

    int cur = 0;
    for (int t = 0; t < KT; ++t) {
        // counted vmcnt BEFORE barrier: own tile-t loads certified, t+1's stay in flight.
        if (t == KT - 1)      asm volatile("s_waitcnt vmcnt(0)" ::: "memory");
        else if (wid < 2)     asm volatile("s_waitcnt vmcnt(5)" ::: "memory");
        else                  asm volatile("s_waitcnt vmcnt(4)" ::: "memory");
        __builtin_amdgcn_s_barrier();
        __builtin_amdgcn_sched_barrier(0);           // pin: no ds_read above the barrier

        const char* bufc = smem + cur * BUFSZ;
        // ---- hoisted fragment reads: BOTH kk halves up front (14 ds_read_b128)
        f16x8 af[2][4], bf[2][3];
#pragma unroll
        for (int kk = 0; kk < 2; ++kk) {
            const int ko = (kk * 64 + lhi * 16) ^ swz;
#pragma unroll
            for (int m = 0; m < 4; ++m)
                af[kk][m] = *reinterpret_cast<const f16x8*>(bufc + (wm * 64 + m * 16 + l15) * 128 + ko);
#pragma unroll
            for (int n = 0; n < 3; ++n)
                bf[kk][n] = *reinterpret_cast<const f16x8*>(bufc + 32768 + (wn * 48 + n * 16 + l15) * 128 + ko);
        }
        // ---- issue next-next tile staging while reads are in flight
        if (t + 2 < KT) {
            int b2 = cur + 2; if (b2 >= 3) b2 -= 3;
            STAGE(t + 2, smem + b2 * BUFSZ);
        }
        // ---- single 24-MFMA cluster (compiler inserts fine-grained lgkmcnt)
        __builtin_amdgcn_s_setprio(1);
#pragma unroll
        for (int kk = 0; kk < 2; ++kk)
#pragma unroll
            for (int m = 0; m < 4; ++m)
#pragma unroll
                for (int n = 0; n < 3; ++n)
                    acc[m][n] = __builtin_amdgcn_mfma_f32_16x16x32_f16(af[kk][m], bf[kk][n], acc[m][n], 0, 0, 0);
        __builtin_amdgcn_s_setprio(0);

        ++cur; if (cur == 3) cur = 0;
    }

    // ---- epilogue: exchange gates via LDS planes, then all threads do gate math
    __syncthreads();
    float* planes = reinterpret_cast<float*>(smem);
    {
        float* myplane = planes + wn * PLANE;
#pragma unroll
        for (int m = 0; m < 4; ++m)
#pragma unroll
            for (int n = 0; n < 3; ++n)
#pragma unroll
                for (int e = 0; e < 4; ++e)
                    myplane[(wm * 64 + m * 16 + lhi * 4 + e) * 52 + n * 16 + l15] = acc[m][n][e];
    }
    __syncthreads();

#pragma unroll
    for (int cc = 0; cc < 2; ++cc) {
        const int c = tid + cc * 768;                 // 1536 chunks of 8
        const int row = c / 6;
        const int coff = (c - row * 6) * 8;
        const int b = gm0 + row;
        const int jb = gn0 + coff;
        if (jb >= HID) continue;
        const float x0 = xprev[b * 4 + 0], x1 = xprev[b * 4 + 1], x2 = xprev[b * 4 + 2];
        const int pb = row * 52 + coff;
        const int nv = (jb + 8 <= HID) ? 8 : (HID - jb);
        float hn[8];
#pragma unroll
        for (int i = 0; i < 8; ++i) {
            if (i < nv) {
                const int j = jb + i;
                const float g0 = planes[pb + i];
                const float g1 = planes[PLANE + pb + i];
                const float g2 = planes[2 * PLANE + pb + i];
                const float* w0 = Wih + (size_t)j * 3;
                const float* w1 = Wih + (size_t)(HID + j) * 3;
                const float* w2 = Wih + (size_t)(2 * HID + j) * 3;
                const float gi0 = x0 * w0[0] + x1 * w0[1] + x2 * w0[2] + bih[j];
                const float gi1 = x0 * w1[0] + x1 * w1[1] + x2 * w1[2] + bih[HID + j];
                const float gi2 = x0 * w2[0] + x1 * w2[1] + x2 * w2[2] + bih[2 * HID + j];
                const float r = sigf(gi0 + g0 + bhh[j]);
                const float u = sigf(gi1 + g1 + bhh[HID + j]);
                const float nn = tanhf_(gi2 + r * (g2 + bhh[2 * HID + j]));
                const float hp_ = hf32[(size_t)b * HP + j];
                hn[i] = (1.f - u) * nn + u * hp_;
            }
        }
        if (nv == 8) {
            f16x8 hv;
#pragma unroll
            for (int i = 0; i < 8; ++i) hv[i] = (f16)hn[i];
            *reinterpret_cast<f16x8*>(h16n + (size_t)b * HP + jb) = hv;
            float4 f0 = {hn[0], hn[1], hn[2], hn[3]};
            float4 f1 = {hn[4], hn[5], hn[6], hn[7]};
            *reinterpret_cast<float4*>(hf32 + (size_t)b * HP + jb) = f0;
            *reinterpret_cast<float4*>(hf32 + (size_t)b * HP + jb + 4) = f1;
        } else {
            for (int i = 0; i < nv; ++i) {
                hf32[(size_t)b * HP + jb + i] = hn[i];
                h16n[(size_t)b * HP + jb + i] = (f16)hn[i];
            }
        }
    }
}

// ---------------- waypoint readout: wave-per-row (4 rows/block), fp32 Wo
__global__ __launch_bounds__(256) void x_update(const f16* __restrict__ hn,
                                                const float* __restrict__ Wo,
                                                const float* __restrict__ bo,
                                                const float* __restrict__ xp,
                                                float* __restrict__ xn,
                                                float* __restrict__ out, int s)
{
    const int w = threadIdx.x >> 6, lane = threadIdx.x & 63;
    const int b = blockIdx.x * 4 + w;
    float a0 = 0.f, a1 = 0.f, a2 = 0.f;
#pragma unroll
    for (int i = 0; i < 6; ++i) {
        const int ch = i * 64 + lane;
        if (ch < 375) {                               // 375*8 = 3000 exactly
            const int k = ch * 8;
            f16x8 h8 = *reinterpret_cast<const f16x8*>(hn + (size_t)b * HP + k);
#pragma unroll
            for (int q = 0; q < 8; ++q) {
                const float hv = (float)h8[q];
                a0 += hv * Wo[k + q];
                a1 += hv * Wo[HID + k + q];
                a2 += hv * Wo[2 * HID + k + q];
            }
        }
    }
#pragma unroll
    for (int off = 32; off; off >>= 1) {
        a0 += __shfl_down(a0, off);
        a1 += __shfl_down(a1, off);
        a2 += __shfl_down(a2, off);
    }
    if (lane == 0) {
        const float r0 = a0 + bo[0] + xp[b * 4 + 0];
        const float r1 = a1 + bo[1] + xp[b * 4 + 1];
        const float r2 = a2 + bo[2] + xp[b * 4 + 2];
        xn[b * 4 + 0] = r0; xn[b * 4 + 1] = r1; xn[b * 4 + 2] = r2;
        float* o = out + ((size_t)b * 30 + s) * 3;
        o[0] = r0; o[1] = r1; o[2] = r2;
    }
}

extern "C" void kernel_launch(void* const* d_in, const int* in_sizes, int n_in,
                              void* d_out, int out_size, void* d_ws, size_t ws_size,
                              hipStream_t stream)
{
    (void)in_sizes; (void)n_in; (void)out_size; (void)ws_size;
    const float* z   = (const float*)d_in[0];
    const float* W1  = (const float*)d_in[1];
    const float* b1  = (const float*)d_in[2];
    const float* W2  = (const float*)d_in[3];
    const float* b2  = (const float*)d_in[4];
    const float* W3  = (const float*)d_in[5];
    const float* b3  = (const float*)d_in[6];
    const float* Wih = (const float*)d_in[7];
    const float* bih = (const float*)d_in[8];
    const float* Whh = (const float*)d_in[9];
    const float* bhh = (const float*)d_in[10];
    const float* Wo  = (const float*)d_in[11];
    const float* bo  = (const float*)d_in[12];
    float* out = (float*)d_out;

    char* ws = (char*)d_ws;
    size_t off = 0;
    f16* whh16 = (f16*)(ws + off); off += (size_t)3 * HP * HP * 2;
    f16* h16[2];
    h16[0] = (f16*)(ws + off); off += (size_t)NB * HP * 2;
    h16[1] = (f16*)(ws + off); off += (size_t)NB * HP * 2;
    float* hf  = (float*)(ws + off); off += (size_t)NB * HP * 4;   // in-place fp32 state
    float* h1  = (float*)(ws + off); off += (size_t)NB * 512 * 4;
    float* h2  = (float*)(ws + off); off += (size_t)NB * 256 * 4;
    f16*   h2h = (f16*)(ws + off);   off += (size_t)NB * 256 * 2;
    f16*   w3f16 = (f16*)(ws + off); off += (size_t)HP * 256 * 2;
    float* xb  = (float*)(ws + off); off += (size_t)31 * NB * 4 * 4;

    // zero both f16 h buffers (pad columns must stay 0 as MFMA K inputs) and x_0
    hipMemsetAsync(h16[0], 0, (size_t)2 * NB * HP * 2, stream);
    hipMemsetAsync(xb, 0, (size_t)NB * 4 * 4, stream);

    {
        int s32 = 3 * HP * (HP / 32);
        convert_whh<<<(s32 + 255) / 256, 256, 0, stream>>>(Whh, whh16);
    }
    convert_w3<<<(HP * 32 + 255) / 256, 256, 0, stream>>>(W3, w3f16);

    mlp_layer<<<NB / 4, 256, 0, stream>>>(z,  256, 512, 512, W1, b1, h1, nullptr);
    mlp_layer<<<NB / 4, 256, 0, stream>>>(h1, 512, 256, 256, W2, b2, h2, h2h);
    mlp3_mfma<<<dim3(HP / BN, NB / BM), 256, 0, stream>>>(h2h, w3f16, b3, hf, h16[0]);

    for (int s = 1; s <= 30; ++s) {
        int cur = (s - 1) & 1, nxt = s & 1;
        gru_step<<<256, 768, 0, stream>>>(
            h16[cur], hf, whh16, xb + (size_t)(s - 1) * NB * 4,
            Wih, bih, bhh, h16[nxt]);
        x_update<<<NB / 4, 256, 0, stream>>>(h16[nxt], Wo, bo,
            xb + (size_t)(s - 1) * NB * 4, xb + (size_t)s * NB * 4, out, s - 1);
    }
}